// Round 2
// baseline (201.989 us; speedup 1.0000x reference)
//
#include <hip/hip_runtime.h>
#include <hip/hip_bf16.h>

typedef __bf16 bf16_t;
typedef __attribute__((ext_vector_type(8))) __bf16 bf16x8;
typedef __attribute__((ext_vector_type(4))) __bf16 bf16x4;
typedef __attribute__((ext_vector_type(4))) float f32x4;

#define MFMA(a, b, c) __builtin_amdgcn_mfma_f32_16x16x32_bf16((a), (b), (c), 0, 0, 0)

// k-dim pad: 260 => row stride 520 B (8 B aligned for ds b64, odd dword-pair
// stride => fragment ds_read_b64 conflict-free, staging writes <=4-way)
#define WK 260

// Device-wide barrier counter. Monotonic across launches: every launch has
// exactly 256 blocks, each adds 1, so each launch occupies one aligned
// 256-epoch — no re-initialization needed (workspace is poisoned every
// iteration, so the counter must NOT live in d_ws).
__device__ unsigned long long g_bar;

static __device__ __forceinline__ bf16x8 zero_bf16x8() {
  bf16x8 z;
#pragma unroll
  for (int i = 0; i < 8; ++i) z[i] = (bf16_t)0.f;
  return z;
}

static __device__ __forceinline__ bf16x8 join8(bf16x4 lo, bf16x4 hi) {
  bf16x8 r;
  r[0] = lo[0]; r[1] = lo[1]; r[2] = lo[2]; r[3] = lo[3];
  r[4] = hi[0]; r[5] = hi[1]; r[6] = hi[2]; r[7] = hi[3];
  return r;
}

static __device__ __forceinline__ bf16x8 cvt8(float4 a, float4 b) {
  bf16x8 r;
  r[0] = (bf16_t)a.x; r[1] = (bf16_t)a.y; r[2] = (bf16_t)a.z; r[3] = (bf16_t)a.w;
  r[4] = (bf16_t)b.x; r[5] = (bf16_t)b.y; r[6] = (bf16_t)b.z; r[7] = (bf16_t)b.w;
  return r;
}

// ---------------------------------------------------------------------------
// Single fused kernel: 256 blocks x 512 threads (8 waves).
//
// Phase 1 (proj): virt = XCD-chunked block id; job = virt>>6, ntile, mtile.
//   Each block: m=128 rows x n=128 cols of one projection. 8 waves of 16
//   rows each (1 A-frag, 8 accs). Weight tile transposed into LDS. The 32
//   m-blocks sharing a weight tile all land on ONE XCD (weight L2-resident).
//   job 0: Q -> Qb, job 1: K -> Kb, job 2: V -> VT [B,H,C,S] via LDS
//   transpose (s-contiguous stores), job 3: G = sigmoid(Vin@GW.T+Gb).
//   All blocks also convert a 256-float slice of OW -> OWb bf16.
//
// Device barrier: guaranteed co-residency (grid=256=#CUs; LDS 66.6KB and
//   launch_bounds(512) => >=1 block/CU capacity => all blocks resident).
//   threadfence release -> atomicAdd -> spin to epoch -> threadfence acquire
//   (device scope handles cross-XCD L2 non-coherence).
//
// Phase 2 (attn): block virt -> q-tile (16 queries); wave h = head h.
//   V/G prefetch -> 5-MFMA scores -> fp32 softmax -> P via LDS -> 6-MFMA PV
//   -> gate -> O tile in LDS -> out = O @ OWb^T + Ob (wave h: n-slice 32).
// ---------------------------------------------------------------------------
__global__ __launch_bounds__(512) void fused_kernel(
    const float* __restrict__ Qin, const float* __restrict__ Kin,
    const float* __restrict__ Vin, const float* __restrict__ QT,
    const float* __restrict__ KT, const float* __restrict__ VTr,
    const float* __restrict__ GW, const float* __restrict__ Gb,
    const float* __restrict__ OW, const float* __restrict__ Ob,
    bf16_t* __restrict__ Qb, bf16_t* __restrict__ Kb,
    bf16_t* __restrict__ VT, bf16_t* __restrict__ G,
    bf16_t* __restrict__ OWb, float* __restrict__ out) {
  __shared__ __align__(16) char smem[128 * WK * 2];  // 66.6 KB, reused per phase
  const int tid = threadIdx.x, lane = tid & 63;
  const int quad = lane >> 4, t15 = lane & 15;
  const int w = tid >> 6;  // wave id 0..7
  // XCD-chunked bijective swizzle (256 = 8 XCDs x 32 contiguous virt ids)
  const int virt = ((blockIdx.x & 7) << 5) | (blockIdx.x >> 3);

  // ---- OW -> bf16, spread across all blocks (256 floats each) ----
  if (tid < 64) {
    const int idx = (int)blockIdx.x * 256 + tid * 4;
    float4 v = *(const float4*)(OW + idx);
    bf16x4 o;
    o[0] = (bf16_t)v.x; o[1] = (bf16_t)v.y; o[2] = (bf16_t)v.z; o[3] = (bf16_t)v.w;
    *(bf16x4*)(OWb + idx) = o;
  }

  // ================= Phase 1: projection =================
  {
    const int job = virt >> 6;           // 0..3
    const int ntile = (virt >> 5) & 1;   // same (job,ntile) => same XCD
    const int mtile = virt & 31;
    const int m0 = mtile * 128 + w * 16;
    const int n0 = ntile * 128;
    const float* A = (job == 0) ? Qin : (job == 1) ? Kin : Vin;
    bf16_t(*Wl)[WK] = (bf16_t(*)[WK])smem;

    if (job < 3) {
      // src [k=256][n=256]; transpose slice into Wl[n][k]. 512 threads:
      // lane covers n (coalesced), 4 k-quads; 16 iters x 4 dword loads.
      const float* src = (job == 0) ? QT : (job == 1) ? KT : VTr;
      const int nl = tid & 127;
      const int kq = (tid >> 7) * 4;  // 0,4,8,12
#pragma unroll 8
      for (int i = 0; i < 16; ++i) {
        int k0 = i * 16 + kq;
        float f0 = src[(size_t)(k0 + 0) * 256 + n0 + nl];
        float f1 = src[(size_t)(k0 + 1) * 256 + n0 + nl];
        float f2 = src[(size_t)(k0 + 2) * 256 + n0 + nl];
        float f3 = src[(size_t)(k0 + 3) * 256 + n0 + nl];
        bf16x4 w4;
        w4[0] = (bf16_t)f0; w4[1] = (bf16_t)f1; w4[2] = (bf16_t)f2; w4[3] = (bf16_t)f3;
        *(bf16x4*)&Wl[nl][k0] = w4;
      }
    } else {
      // GW is [n=256][k=256] (nn.Linear [out,in]); straight cast.
      const int kk = (tid & 63) * 4;
      const int nw = tid >> 6;
#pragma unroll 8
      for (int i = 0; i < 16; ++i) {
        int n = i * 8 + nw;
        float4 v = *(const float4*)(GW + (size_t)(n0 + n) * 256 + kk);
        bf16x4 w4;
        w4[0] = (bf16_t)v.x; w4[1] = (bf16_t)v.y; w4[2] = (bf16_t)v.z; w4[3] = (bf16_t)v.w;
        *(bf16x4*)&Wl[n][kk] = w4;
      }
    }
    __syncthreads();

    const f32x4 zf = {0.f, 0.f, 0.f, 0.f};
    f32x4 acc[8];
#pragma unroll
    for (int nf = 0; nf < 8; ++nf) acc[nf] = zf;

    for (int kc = 0; kc < 8; ++kc) {
      const float* ap = A + (size_t)(m0 + t15) * 256 + kc * 32 + quad * 8;
      float4 x0 = *(const float4*)ap;
      float4 x1 = *(const float4*)(ap + 4);
      bf16x8 a = cvt8(x0, x1);
#pragma unroll
      for (int nf = 0; nf < 8; ++nf) {
        bf16x4 lo = *(const bf16x4*)&Wl[nf * 16 + t15][kc * 32 + quad * 8];
        bf16x4 hi = *(const bf16x4*)&Wl[nf * 16 + t15][kc * 32 + quad * 8 + 4];
        acc[nf] = MFMA(a, join8(lo, hi), acc[nf]);
      }
    }

    if (job == 2) {
      // LDS transpose so the [h,c,s] global store is s-contiguous.
      __syncthreads();  // all waves done reading Wl
      bf16_t* Sb = (bf16_t*)smem;  // [n=128][stride 136]
      {
        const int m = w * 16 + quad * 4;
#pragma unroll
        for (int nf = 0; nf < 8; ++nf) {
          const int n = nf * 16 + t15;
          bf16x4 v4;
#pragma unroll
          for (int r = 0; r < 4; ++r) v4[r] = (bf16_t)acc[nf][r];
          *(bf16x4*)&Sb[n * 136 + m] = v4;
        }
      }
      __syncthreads();
      const int mloc = (tid & 15) * 8;  // 16 lanes cover 128 m-rows
      const int nl2 = tid >> 4;         // 32 n-columns per pass
      const int mg = mtile * 128 + mloc;
      const int bb = mg >> 11, s = mg & 2047;
#pragma unroll
      for (int p = 0; p < 4; ++p) {
        const int ng = n0 + p * 32 + nl2;
        const int hh = ng >> 5, c = ng & 31;
        bf16x8 v = *(const bf16x8*)&Sb[(p * 32 + nl2) * 136 + mloc];
        *(bf16x8*)(VT + (size_t)((bb * 8 + hh) * 32 + c) * 2048 + s) = v;
      }
    } else if (job == 3) {
      const int mm0 = m0 + quad * 4;
#pragma unroll
      for (int nf = 0; nf < 8; ++nf) {
        int nn = n0 + nf * 16 + t15;
        float bias = Gb[nn];
#pragma unroll
        for (int r = 0; r < 4; ++r) {
          float g = 1.f / (1.f + __expf(-(acc[nf][r] + bias)));
          G[(size_t)(mm0 + r) * 256 + nn] = (bf16_t)g;
        }
      }
    } else {
      bf16_t* dst = (job == 0) ? Qb : Kb;
      const int mm0 = m0 + quad * 4;
#pragma unroll
      for (int nf = 0; nf < 8; ++nf) {
        int nn = n0 + nf * 16 + t15;
#pragma unroll
        for (int r = 0; r < 4; ++r)
          dst[(size_t)(mm0 + r) * 256 + nn] = (bf16_t)acc[nf][r];
      }
    }
  }

  // ================= Device-wide barrier =================
  __threadfence();   // release: push phase-1 stores to device scope (wbl2)
  __syncthreads();
  if (tid == 0) {
    unsigned long long c = atomicAdd(&g_bar, 1ull);
    unsigned long long target = (c & ~255ull) + 256ull;  // end of this epoch
    while (__hip_atomic_load(&g_bar, __ATOMIC_RELAXED, __HIP_MEMORY_SCOPE_AGENT) < target)
      __builtin_amdgcn_s_sleep(2);
  }
  __syncthreads();
  __threadfence();   // acquire: invalidate stale L1/L2 before cross-block reads

  // ================= Phase 2: windowed attention + out-proj =================
  {
    bf16_t(*P)[16][104] = (bf16_t(*)[16][104])smem;              // 26.6 KB
    bf16_t(*Ol)[WK] = (bf16_t(*)[WK])(smem + 8 * 16 * 104 * 2);  // 8.3 KB
    const int h = w;
    const int qt = virt & 127, b = virt >> 7;
    const int q0 = qt * 16, tbase = q0 - 32;
    const size_t rowbase = (size_t)b * 2048;

    // Q A-fragment (K=32 = full head dim)
    bf16x8 aq = *(const bf16x8*)(Qb + (rowbase + q0 + t15) * 256 + h * 32 + quad * 8);

    // prefetch V B-fragments — independent of scores, hides latency under QK^T
    bf16x8 bv[3][2];
#pragma unroll
    for (int kc = 0; kc < 3; ++kc) {
      int ts = tbase + kc * 32 + quad * 8;  // multiple of 8: chunk fully in/out
      bv[kc][0] = zero_bf16x8();
      bv[kc][1] = zero_bf16x8();
      if (ts >= 0 && ts + 8 <= 2048) {
        const bf16_t* vb = VT + ((size_t)((b * 8 + h) * 32) + t15) * 2048 + ts;
        bv[kc][0] = *(const bf16x8*)vb;
        bv[kc][1] = *(const bf16x8*)(vb + (size_t)16 * 2048);
      }
    }

    // prefetch gate values (used only after PV)
    float g0[4], g1[4];
#pragma unroll
    for (int r = 0; r < 4; ++r) {
      size_t base = (rowbase + q0 + quad * 4 + r) * 256 + h * 32;
      g0[r] = (float)G[base + t15];
      g1[r] = (float)G[base + 16 + t15];
    }
    const float ob0 = Ob[h * 32 + t15];
    const float ob1 = Ob[h * 32 + 16 + t15];

    const f32x4 zf = {0.f, 0.f, 0.f, 0.f};
    f32x4 sc[5];
#pragma unroll
    for (int j = 0; j < 5; ++j) {
      int t = tbase + j * 16 + t15;
      bf16x8 bk = zero_bf16x8();
      if ((unsigned)t < 2048u)
        bk = *(const bf16x8*)(Kb + (rowbase + t) * 256 + h * 32 + quad * 8);
      sc[j] = MFMA(aq, bk, zf);
    }

    const float scale = 0.17677669529663687f;  // 1/sqrt(32)
    float mx[4] = {-3.0e38f, -3.0e38f, -3.0e38f, -3.0e38f};
#pragma unroll
    for (int j = 0; j < 5; ++j) {
      int t = tbase + j * 16 + t15;
#pragma unroll
      for (int r = 0; r < 4; ++r) {
        int q = q0 + quad * 4 + r;
        int dd = q - t;
        bool valid = ((unsigned)t < 2048u) && (dd <= 32) && (dd >= -32);
        float v = valid ? sc[j][r] * scale : -1e30f;
        sc[j][r] = v;
        mx[r] = fmaxf(mx[r], v);
      }
    }
#pragma unroll
    for (int off = 1; off < 16; off <<= 1) {
#pragma unroll
      for (int r = 0; r < 4; ++r) mx[r] = fmaxf(mx[r], __shfl_xor(mx[r], off));
    }
    float sum[4] = {0.f, 0.f, 0.f, 0.f};
#pragma unroll
    for (int j = 0; j < 5; ++j) {
#pragma unroll
      for (int r = 0; r < 4; ++r) {
        float e = __expf(sc[j][r] - mx[r]);
        sc[j][r] = e;
        sum[r] += e;
      }
    }
#pragma unroll
    for (int off = 1; off < 16; off <<= 1) {
#pragma unroll
      for (int r = 0; r < 4; ++r) sum[r] += __shfl_xor(sum[r], off);
    }
    float inv[4];
#pragma unroll
    for (int r = 0; r < 4; ++r) inv[r] = 1.f / sum[r];

    // C-layout -> LDS rows q_local, cols t_local (80..95 zero pad)
#pragma unroll
    for (int j = 0; j < 5; ++j) {
#pragma unroll
      for (int r = 0; r < 4; ++r)
        P[h][quad * 4 + r][j * 16 + t15] = (bf16_t)(sc[j][r] * inv[r]);
    }
#pragma unroll
    for (int r = 0; r < 4; ++r) P[h][quad * 4 + r][80 + t15] = (bf16_t)0.f;
    __syncthreads();

    f32x4 y0 = zf, y1 = zf;
#pragma unroll
    for (int kc = 0; kc < 3; ++kc) {
      bf16x8 pa = *(const bf16x8*)&P[h][t15][kc * 32 + quad * 8];
      y0 = MFMA(pa, bv[kc][0], y0);
      y1 = MFMA(pa, bv[kc][1], y1);
    }

    // gate and gather the 16x256 O tile into LDS
#pragma unroll
    for (int r = 0; r < 4; ++r) {
      Ol[quad * 4 + r][h * 32 + t15] = (bf16_t)(y0[r] * g0[r]);
      Ol[quad * 4 + r][h * 32 + 16 + t15] = (bf16_t)(y1[r] * g1[r]);
    }
    __syncthreads();

    // out-projection: wave h computes out[:, h*32 .. h*32+32) from bf16 OWb
    f32x4 acc2[2] = {zf, zf};
#pragma unroll
    for (int kc = 0; kc < 8; ++kc) {
      bf16x4 alo = *(const bf16x4*)&Ol[t15][kc * 32 + quad * 8];
      bf16x4 ahi = *(const bf16x4*)&Ol[t15][kc * 32 + quad * 8 + 4];
      bf16x8 a = join8(alo, ahi);
#pragma unroll
      for (int nf = 0; nf < 2; ++nf) {
        int n = h * 32 + nf * 16 + t15;
        bf16x8 w8 = *(const bf16x8*)(OWb + (size_t)n * 256 + kc * 32 + quad * 8);
        acc2[nf] = MFMA(a, w8, acc2[nf]);
      }
    }
#pragma unroll
    for (int nf = 0; nf < 2; ++nf) {
      int n = h * 32 + nf * 16 + t15;
      float bias = (nf == 0) ? ob0 : ob1;
#pragma unroll
      for (int r = 0; r < 4; ++r)
        out[(rowbase + q0 + quad * 4 + r) * 256 + n] = acc2[nf][r] + bias;
    }
  }
}

// ---------------------------------------------------------------------------
extern "C" void kernel_launch(void* const* d_in, const int* in_sizes, int n_in,
                              void* d_out, int out_size, void* d_ws, size_t ws_size,
                              hipStream_t stream) {
  const float* Qin = (const float*)d_in[0];
  const float* Kin = (const float*)d_in[1];
  const float* Vin = (const float*)d_in[2];
  const float* QT  = (const float*)d_in[3];
  const float* KT  = (const float*)d_in[4];
  const float* VTr = (const float*)d_in[5];
  const float* GW  = (const float*)d_in[6];
  const float* Gb  = (const float*)d_in[7];
  const float* OW  = (const float*)d_in[8];
  const float* Ob  = (const float*)d_in[9];
  float* out = (float*)d_out;

  char* ws = (char*)d_ws;
  const size_t MB = 1u << 20;
  bf16_t* Qb  = (bf16_t*)(ws + 0 * MB);  // [B,S,256] bf16, 2 MB
  bf16_t* Kb  = (bf16_t*)(ws + 2 * MB);  // [B,S,256] bf16, 2 MB
  bf16_t* VT  = (bf16_t*)(ws + 4 * MB);  // [B,H,C,S] bf16, 2 MB
  bf16_t* G   = (bf16_t*)(ws + 6 * MB);  // [B,S,256] bf16, 2 MB
  bf16_t* OWb = (bf16_t*)(ws + 8 * MB);  // [256,256] bf16, 128 KB

  fused_kernel<<<256, 512, 0, stream>>>(Qin, Kin, Vin, QT, KT, VTr, GW, Gb,
                                        OW, Ob, Qb, Kb, VT, G, OWb, out);
}

// Round 3
// 105.025 us; speedup vs baseline: 1.9233x; 1.9233x over previous
//
#include <hip/hip_runtime.h>
#include <hip/hip_bf16.h>

typedef __bf16 bf16_t;
typedef __attribute__((ext_vector_type(8))) __bf16 bf16x8;
typedef __attribute__((ext_vector_type(4))) __bf16 bf16x4;
typedef __attribute__((ext_vector_type(4))) float f32x4;

#define MFMA(a, b, c) __builtin_amdgcn_mfma_f32_16x16x32_bf16((a), (b), (c), 0, 0, 0)

// k-dim pad: 260 => row stride 520 B (8 B aligned for ds b64, odd dword-pair
// stride => fragment ds_read_b64 conflict-free, staging writes <=4-way)
#define WK 260
// epilogue store-transpose stride: 132 elems = 264 B rows; 4-row (quad) step
// = 264 dwords ≡ 8 (mod 32) banks => quads hit disjoint bank octets on write
#define SN 132

static __device__ __forceinline__ bf16x8 zero_bf16x8() {
  bf16x8 z;
#pragma unroll
  for (int i = 0; i < 8; ++i) z[i] = (bf16_t)0.f;
  return z;
}

static __device__ __forceinline__ bf16x8 join8(bf16x4 lo, bf16x4 hi) {
  bf16x8 r;
  r[0] = lo[0]; r[1] = lo[1]; r[2] = lo[2]; r[3] = lo[3];
  r[4] = hi[0]; r[5] = hi[1]; r[6] = hi[2]; r[7] = hi[3];
  return r;
}

static __device__ __forceinline__ bf16x8 cvt8(float4 a, float4 b) {
  bf16x8 r;
  r[0] = (bf16_t)a.x; r[1] = (bf16_t)a.y; r[2] = (bf16_t)a.z; r[3] = (bf16_t)a.w;
  r[4] = (bf16_t)b.x; r[5] = (bf16_t)b.y; r[6] = (bf16_t)b.z; r[7] = (bf16_t)b.w;
  return r;
}

// ---------------------------------------------------------------------------
// Kernel 1: projections with in-block weight transpose to LDS.
// grid (Mtiles=32, Ntiles=2, job=5), 256 thr = 4 waves.
// Each block: m=128 rows x n=128 cols. Wave w covers m-subtiles
// {w*16, w*16+64}; 2x8 MFMA accs per wave.
// job 0: Q=Qin@QTrans -> Qb bf16 [B,S,256]
// job 1: K=Kin@KTrans -> Kb bf16 [B,S,256]
// job 2: V=Vin@VTrans -> VT bf16 [B,H,C,S] via LDS transpose
// job 3: G=sigmoid(Vin@GW.T+Gb) -> G bf16 [B,S,256]
// job 4: OW fp32 -> OWb bf16 (4 working blocks; rest exit immediately)
// Jobs 0/1/3 epilogue: C goes through LDS [m][n] so global stores are
// coalesced bf16x8 (was 64 scalar 2B stores/thread -> 8 16B stores/thread).
// ---------------------------------------------------------------------------
__global__ __launch_bounds__(256) void proj_kernel(
    const float* __restrict__ Qin, const float* __restrict__ Kin,
    const float* __restrict__ Vin, const float* __restrict__ QT,
    const float* __restrict__ KT, const float* __restrict__ VTr,
    const float* __restrict__ GW, const float* __restrict__ Gb,
    const float* __restrict__ OW,
    bf16_t* __restrict__ Qb, bf16_t* __restrict__ Kb,
    bf16_t* __restrict__ VT, bf16_t* __restrict__ G,
    bf16_t* __restrict__ OWb) {
  __shared__ bf16_t Wl[128][WK];  // 66.6 KB static LDS (gfx950: 160 KB/CU)
  const int tid = threadIdx.x, w = tid >> 6, lane = tid & 63;
  const int quad = lane >> 4, t15 = lane & 15;
  const int job = blockIdx.z;

  if (job == 4) {  // one-time OW -> bf16 conversion, coalesced 4KB/instr
    if (blockIdx.y != 0 || blockIdx.x >= 4) return;
    const int base = blockIdx.x * 16384 + tid * 4;
#pragma unroll
    for (int i = 0; i < 16; ++i) {
      int idx = base + i * 1024;
      float4 v = *(const float4*)(OW + idx);
      bf16x4 o;
      o[0] = (bf16_t)v.x; o[1] = (bf16_t)v.y;
      o[2] = (bf16_t)v.z; o[3] = (bf16_t)v.w;
      *(bf16x4*)(OWb + idx) = o;
    }
    return;
  }

  const int m0 = blockIdx.x * 128 + w * 16;
  const int n0 = blockIdx.y * 128;
  const float* A = (job == 0) ? Qin : (job == 1) ? Kin : Vin;

  // --- stage weight tile [k=0..255][n=n0..n0+127] into Wl[n][k] (bf16) ---
  if (job < 3) {
    // src is [k=256][n=256]; transpose. Coalesced along n (128 lanes/row).
    const float* src = (job == 0) ? QT : (job == 1) ? KT : VTr;
    const int nl = tid & 127;
    const int kq = (tid >> 7) * 4;  // 0 or 4
#pragma unroll 8
    for (int i = 0; i < 32; ++i) {
      int k0 = i * 8 + kq;
      float f0 = src[(size_t)(k0 + 0) * 256 + n0 + nl];
      float f1 = src[(size_t)(k0 + 1) * 256 + n0 + nl];
      float f2 = src[(size_t)(k0 + 2) * 256 + n0 + nl];
      float f3 = src[(size_t)(k0 + 3) * 256 + n0 + nl];
      bf16x4 w4;
      w4[0] = (bf16_t)f0; w4[1] = (bf16_t)f1; w4[2] = (bf16_t)f2; w4[3] = (bf16_t)f3;
      *(bf16x4*)&Wl[nl][k0] = w4;
    }
  } else {
    // GW is [n=256][k=256] (nn.Linear [out,in]); straight cast.
    const int kk = (tid & 63) * 4;
    const int nw = tid >> 6;
#pragma unroll 8
    for (int i = 0; i < 32; ++i) {
      int n = i * 4 + nw;
      float4 v = *(const float4*)(GW + (size_t)(n0 + n) * 256 + kk);
      bf16x4 w4;
      w4[0] = (bf16_t)v.x; w4[1] = (bf16_t)v.y; w4[2] = (bf16_t)v.z; w4[3] = (bf16_t)v.w;
      *(bf16x4*)&Wl[n][kk] = w4;
    }
  }
  __syncthreads();

  const f32x4 zf = {0.f, 0.f, 0.f, 0.f};
  f32x4 acc[2][8];
#pragma unroll
  for (int mi = 0; mi < 2; ++mi)
#pragma unroll
    for (int nf = 0; nf < 8; ++nf) acc[mi][nf] = zf;

  for (int kc = 0; kc < 8; ++kc) {
    bf16x8 a[2];
#pragma unroll
    for (int mi = 0; mi < 2; ++mi) {
      const float* ap = A + (size_t)(m0 + mi * 64 + t15) * 256 + kc * 32 + quad * 8;
      float4 x0 = *(const float4*)ap;
      float4 x1 = *(const float4*)(ap + 4);
      a[mi] = cvt8(x0, x1);
    }
#pragma unroll
    for (int nf = 0; nf < 8; ++nf) {
      bf16x4 lo = *(const bf16x4*)&Wl[nf * 16 + t15][kc * 32 + quad * 8];
      bf16x4 hi = *(const bf16x4*)&Wl[nf * 16 + t15][kc * 32 + quad * 8 + 4];
      bf16x8 bw = join8(lo, hi);
#pragma unroll
      for (int mi = 0; mi < 2; ++mi) acc[mi][nf] = MFMA(a[mi], bw, acc[mi][nf]);
    }
  }

  if (job == 2) {
    // Wl is dead; alias it as Sl[n=128][stride 136] and transpose in LDS so
    // the [h,c,s] global store is s-contiguous per 16-lane group.
    __syncthreads();
    bf16_t* Sb = &Wl[0][0];
#pragma unroll
    for (int mi = 0; mi < 2; ++mi) {
      const int m = mi * 64 + w * 16 + quad * 4;
#pragma unroll
      for (int nf = 0; nf < 8; ++nf) {
        const int n = nf * 16 + t15;
#pragma unroll
        for (int r = 0; r < 4; ++r) Sb[n * 136 + m + r] = (bf16_t)acc[mi][nf][r];
      }
    }
    __syncthreads();
    const int mloc = (tid & 15) * 8;  // lanes 0..15 cover 128 m-rows
    const int nl2 = tid >> 4;         // 16 n-columns per pass
    const int mg = blockIdx.x * 128 + mloc;
    const int bb = mg >> 11, s = mg & 2047;
#pragma unroll
    for (int p = 0; p < 8; ++p) {
      const int ng = n0 + p * 16 + nl2;
      const int hh = ng >> 5, c = ng & 31;
      bf16x8 v = *(const bf16x8*)&Sb[(p * 16 + nl2) * 136 + mloc];
      *(bf16x8*)(VT + (size_t)((bb * 8 + hh) * 32 + c) * 2048 + s) = v;
    }
  } else {
    // jobs 0,1,3: C -> LDS [m][n] (stride SN) -> coalesced bf16x8 stores
    __syncthreads();  // all waves done reading Wl
    bf16_t* Sb = &Wl[0][0];
#pragma unroll
    for (int mi = 0; mi < 2; ++mi) {
      const int m = mi * 64 + w * 16 + quad * 4;
#pragma unroll
      for (int nf = 0; nf < 8; ++nf) {
        if (job == 3) {
          float bias = Gb[n0 + nf * 16 + t15];
#pragma unroll
          for (int r = 0; r < 4; ++r) {
            float g = 1.f / (1.f + __expf(-(acc[mi][nf][r] + bias)));
            Sb[(m + r) * SN + nf * 16 + t15] = (bf16_t)g;
          }
        } else {
#pragma unroll
          for (int r = 0; r < 4; ++r)
            Sb[(m + r) * SN + nf * 16 + t15] = (bf16_t)acc[mi][nf][r];
        }
      }
    }
    __syncthreads();
    bf16_t* dst = (job == 0) ? Qb : (job == 1) ? Kb : G;
    const int row = tid >> 1, cs = (tid & 1) * 64;  // 2 thr/row, 64 cols each
    const size_t gbase = (size_t)(blockIdx.x * 128 + row) * 256 + n0 + cs;
#pragma unroll
    for (int i = 0; i < 8; ++i) {
      bf16x4 vlo = *(const bf16x4*)&Sb[row * SN + cs + i * 8];
      bf16x4 vhi = *(const bf16x4*)&Sb[row * SN + cs + i * 8 + 4];
      *(bf16x8*)(dst + gbase + i * 8) = join8(vlo, vhi);
    }
  }
}

// ---------------------------------------------------------------------------
// Kernel 2: fused windowed attention + gating + output projection.
// 512 threads = 8 waves; wave h handles head h of one 16-query tile.
// V B-fragments + gate values prefetched before the score phase. P tile is
// WAVE-PRIVATE (written and read only by wave h) => no barrier between
// softmax and PV; the only __syncthreads is before the out-projection
// (cross-wave Ol reads). Out-projection consumes pre-converted bf16 OWb.
// XCD-swizzled block mapping keeps neighboring q-tiles on one XCD L2.
// grid = B*S/16 = 256 blocks.
// ---------------------------------------------------------------------------
__global__ __launch_bounds__(512) void attn_out_kernel(
    const bf16_t* __restrict__ Qb, const bf16_t* __restrict__ Kb,
    const bf16_t* __restrict__ VT, const bf16_t* __restrict__ G,
    const bf16_t* __restrict__ OWb, const float* __restrict__ Ob,
    float* __restrict__ out) {
  __shared__ bf16_t P[8][16][104];  // per-wave P tile (C->A layout transform)
  __shared__ bf16_t Ol[16][WK];     // gated attention output tile, [q_local][k]
  const int tid = threadIdx.x, h = tid >> 6, lane = tid & 63;
  const int quad = lane >> 4, t15 = lane & 15;
  // XCD-aware swizzle: 256 blocks = 8 XCDs x 32 contiguous q-tiles (bijective)
  const int bid = ((blockIdx.x & 7) << 5) | (blockIdx.x >> 3);
  const int qt = bid & 127, b = bid >> 7;
  const int q0 = qt * 16, tbase = q0 - 32;
  const size_t rowbase = (size_t)b * 2048;

  // Q A-fragment (K=32 = full head dim)
  bf16x8 aq = *(const bf16x8*)(Qb + (rowbase + q0 + t15) * 256 + h * 32 + quad * 8);

  // prefetch V B-fragments — independent of scores, hides latency under QK^T
  bf16x8 bv[3][2];
#pragma unroll
  for (int kc = 0; kc < 3; ++kc) {
    int ts = tbase + kc * 32 + quad * 8;  // multiple of 8: chunk fully in/out
    bv[kc][0] = zero_bf16x8();
    bv[kc][1] = zero_bf16x8();
    if (ts >= 0 && ts + 8 <= 2048) {
      const bf16_t* vb = VT + ((size_t)((b * 8 + h) * 32) + t15) * 2048 + ts;
      bv[kc][0] = *(const bf16x8*)vb;
      bv[kc][1] = *(const bf16x8*)(vb + (size_t)16 * 2048);
    }
  }

  // prefetch gate values (used only after PV)
  float g0[4], g1[4];
#pragma unroll
  for (int r = 0; r < 4; ++r) {
    size_t base = (rowbase + q0 + quad * 4 + r) * 256 + h * 32;
    g0[r] = (float)G[base + t15];
    g1[r] = (float)G[base + 16 + t15];
  }
  const float ob0 = Ob[h * 32 + t15];
  const float ob1 = Ob[h * 32 + 16 + t15];

  const f32x4 zf = {0.f, 0.f, 0.f, 0.f};
  f32x4 sc[5];
#pragma unroll
  for (int j = 0; j < 5; ++j) {
    int t = tbase + j * 16 + t15;
    bf16x8 bk = zero_bf16x8();
    if ((unsigned)t < 2048u)
      bk = *(const bf16x8*)(Kb + (rowbase + t) * 256 + h * 32 + quad * 8);
    sc[j] = MFMA(aq, bk, zf);
  }

  const float scale = 0.17677669529663687f;  // 1/sqrt(32)
  float mx[4] = {-3.0e38f, -3.0e38f, -3.0e38f, -3.0e38f};
#pragma unroll
  for (int j = 0; j < 5; ++j) {
    int t = tbase + j * 16 + t15;
#pragma unroll
    for (int r = 0; r < 4; ++r) {
      int q = q0 + quad * 4 + r;
      int dd = q - t;
      bool valid = ((unsigned)t < 2048u) && (dd <= 32) && (dd >= -32);
      float v = valid ? sc[j][r] * scale : -1e30f;
      sc[j][r] = v;
      mx[r] = fmaxf(mx[r], v);
    }
  }
#pragma unroll
  for (int off = 1; off < 16; off <<= 1) {
#pragma unroll
    for (int r = 0; r < 4; ++r) mx[r] = fmaxf(mx[r], __shfl_xor(mx[r], off));
  }
  float sum[4] = {0.f, 0.f, 0.f, 0.f};
#pragma unroll
  for (int j = 0; j < 5; ++j) {
#pragma unroll
    for (int r = 0; r < 4; ++r) {
      float e = __expf(sc[j][r] - mx[r]);
      sc[j][r] = e;
      sum[r] += e;
    }
  }
#pragma unroll
  for (int off = 1; off < 16; off <<= 1) {
#pragma unroll
    for (int r = 0; r < 4; ++r) sum[r] += __shfl_xor(sum[r], off);
  }
  float inv[4];
#pragma unroll
  for (int r = 0; r < 4; ++r) inv[r] = 1.f / sum[r];

  // C-layout -> LDS rows q_local, cols t_local (80..95 zero pad).
  // P[h] is wave-private: same-wave DS ordering + compiler lgkmcnt make a
  // block barrier unnecessary here.
#pragma unroll
  for (int j = 0; j < 5; ++j) {
#pragma unroll
    for (int r = 0; r < 4; ++r)
      P[h][quad * 4 + r][j * 16 + t15] = (bf16_t)(sc[j][r] * inv[r]);
  }
#pragma unroll
  for (int r = 0; r < 4; ++r) P[h][quad * 4 + r][80 + t15] = (bf16_t)0.f;

  f32x4 y0 = zf, y1 = zf;
#pragma unroll
  for (int kc = 0; kc < 3; ++kc) {
    bf16x8 pa = *(const bf16x8*)&P[h][t15][kc * 32 + quad * 8];
    y0 = MFMA(pa, bv[kc][0], y0);
    y1 = MFMA(pa, bv[kc][1], y1);
  }

  // gate and gather the 16x256 O tile into LDS
#pragma unroll
  for (int r = 0; r < 4; ++r) {
    Ol[quad * 4 + r][h * 32 + t15] = (bf16_t)(y0[r] * g0[r]);
    Ol[quad * 4 + r][h * 32 + 16 + t15] = (bf16_t)(y1[r] * g1[r]);
  }
  __syncthreads();

  // out-projection: wave h computes out[:, h*32 .. h*32+32) from bf16 OWb
  f32x4 acc[2] = {zf, zf};
#pragma unroll
  for (int kc = 0; kc < 8; ++kc) {
    bf16x4 alo = *(const bf16x4*)&Ol[t15][kc * 32 + quad * 8];
    bf16x4 ahi = *(const bf16x4*)&Ol[t15][kc * 32 + quad * 8 + 4];
    bf16x8 a = join8(alo, ahi);
#pragma unroll
    for (int nf = 0; nf < 2; ++nf) {
      int n = h * 32 + nf * 16 + t15;
      bf16x8 w8 = *(const bf16x8*)(OWb + (size_t)n * 256 + kc * 32 + quad * 8);
      acc[nf] = MFMA(a, w8, acc[nf]);
    }
  }
#pragma unroll
  for (int nf = 0; nf < 2; ++nf) {
    int n = h * 32 + nf * 16 + t15;
    float bias = (nf == 0) ? ob0 : ob1;
#pragma unroll
    for (int r = 0; r < 4; ++r)
      out[(rowbase + q0 + quad * 4 + r) * 256 + n] = acc[nf][r] + bias;
  }
}

// ---------------------------------------------------------------------------
extern "C" void kernel_launch(void* const* d_in, const int* in_sizes, int n_in,
                              void* d_out, int out_size, void* d_ws, size_t ws_size,
                              hipStream_t stream) {
  const float* Qin = (const float*)d_in[0];
  const float* Kin = (const float*)d_in[1];
  const float* Vin = (const float*)d_in[2];
  const float* QT  = (const float*)d_in[3];
  const float* KT  = (const float*)d_in[4];
  const float* VTr = (const float*)d_in[5];
  const float* GW  = (const float*)d_in[6];
  const float* Gb  = (const float*)d_in[7];
  const float* OW  = (const float*)d_in[8];
  const float* Ob  = (const float*)d_in[9];
  float* out = (float*)d_out;

  char* ws = (char*)d_ws;
  const size_t MB = 1u << 20;
  bf16_t* Qb  = (bf16_t*)(ws + 0 * MB);  // [B,S,256] bf16, 2 MB
  bf16_t* Kb  = (bf16_t*)(ws + 2 * MB);  // [B,S,256] bf16, 2 MB
  bf16_t* VT  = (bf16_t*)(ws + 4 * MB);  // [B,H,C,S] bf16, 2 MB
  bf16_t* G   = (bf16_t*)(ws + 6 * MB);  // [B,S,256] bf16, 2 MB
  bf16_t* OWb = (bf16_t*)(ws + 8 * MB);  // [256,256] bf16, 128 KB

  proj_kernel<<<dim3(32, 2, 5), 256, 0, stream>>>(Qin, Kin, Vin, QT, KT, VTr,
                                                  GW, Gb, OW, Qb, Kb, VT, G, OWb);
  attn_out_kernel<<<256, 512, 0, stream>>>(Qb, Kb, VT, G, OWb, Ob, out);
}

// Round 4
// 101.250 us; speedup vs baseline: 1.9949x; 1.0373x over previous
//
#include <hip/hip_runtime.h>
#include <hip/hip_bf16.h>

typedef __bf16 bf16_t;
typedef __attribute__((ext_vector_type(8))) __bf16 bf16x8;
typedef __attribute__((ext_vector_type(4))) __bf16 bf16x4;
typedef __attribute__((ext_vector_type(4))) float f32x4;

#define MFMA(a, b, c) __builtin_amdgcn_mfma_f32_16x16x32_bf16((a), (b), (c), 0, 0, 0)

// k-dim pad: 260 => row stride 520 B (8 B aligned for ds b64, odd dword-pair
// stride => fragment ds_read_b64 conflict-free, staging writes <=4-way)
#define WK 260

static __device__ __forceinline__ bf16x8 zero_bf16x8() {
  bf16x8 z;
#pragma unroll
  for (int i = 0; i < 8; ++i) z[i] = (bf16_t)0.f;
  return z;
}

static __device__ __forceinline__ bf16x8 join8(bf16x4 lo, bf16x4 hi) {
  bf16x8 r;
  r[0] = lo[0]; r[1] = lo[1]; r[2] = lo[2]; r[3] = lo[3];
  r[4] = hi[0]; r[5] = hi[1]; r[6] = hi[2]; r[7] = hi[3];
  return r;
}

static __device__ __forceinline__ bf16x8 cvt8(float4 a, float4 b) {
  bf16x8 r;
  r[0] = (bf16_t)a.x; r[1] = (bf16_t)a.y; r[2] = (bf16_t)a.z; r[3] = (bf16_t)a.w;
  r[4] = (bf16_t)b.x; r[5] = (bf16_t)b.y; r[6] = (bf16_t)b.z; r[7] = (bf16_t)b.w;
  return r;
}

// ---------------------------------------------------------------------------
// Kernel 1: projections with in-block weight transpose to LDS.
// grid (Mtiles=32, Ntiles=2, job=5), 256 thr = 4 waves.
// Each block: m=128 rows x n=128 cols. Wave w covers m-subtiles
// {w*16, w*16+64}; 2x8 MFMA accs per wave.
// job 0: Q=Qin@QTrans -> Qb bf16 [B,S,256]
// job 1: K=Kin@KTrans -> Kb bf16 [B,S,256]
// job 2: V=Vin@VTrans -> VT bf16 [B,H,C,S] via LDS transpose
//        (s-contiguous 16B stores; direct stores would be 8B scatter at
//        4KB stride — this one genuinely needs the LDS path)
// job 3: G=sigmoid(Vin@GW.T+Gb) -> G bf16 [B,S,256]
// job 4: OW fp32 -> OWb bf16 (4 working blocks; rest exit immediately)
// Jobs 0/1/3 store DIRECTLY from the accumulator: 16-lane groups write 32B
// contiguous segments; L2 write-combining handles this fine (R3 post-mortem:
// routing these through LDS added 2 barriers + LDS traffic and LOST ~2.5us).
// ---------------------------------------------------------------------------
__global__ __launch_bounds__(256) void proj_kernel(
    const float* __restrict__ Qin, const float* __restrict__ Kin,
    const float* __restrict__ Vin, const float* __restrict__ QT,
    const float* __restrict__ KT, const float* __restrict__ VTr,
    const float* __restrict__ GW, const float* __restrict__ Gb,
    const float* __restrict__ OW,
    bf16_t* __restrict__ Qb, bf16_t* __restrict__ Kb,
    bf16_t* __restrict__ VT, bf16_t* __restrict__ G,
    bf16_t* __restrict__ OWb) {
  __shared__ bf16_t Wl[128][WK];  // 66.6 KB static LDS (gfx950: 160 KB/CU)
  const int tid = threadIdx.x, w = tid >> 6, lane = tid & 63;
  const int quad = lane >> 4, t15 = lane & 15;
  const int job = blockIdx.z;

  if (job == 4) {  // one-time OW -> bf16 conversion, coalesced 4KB/instr
    if (blockIdx.y != 0 || blockIdx.x >= 4) return;
    const int base = blockIdx.x * 16384 + tid * 4;
#pragma unroll
    for (int i = 0; i < 16; ++i) {
      int idx = base + i * 1024;
      float4 v = *(const float4*)(OW + idx);
      bf16x4 o;
      o[0] = (bf16_t)v.x; o[1] = (bf16_t)v.y;
      o[2] = (bf16_t)v.z; o[3] = (bf16_t)v.w;
      *(bf16x4*)(OWb + idx) = o;
    }
    return;
  }

  const int m0 = blockIdx.x * 128 + w * 16;
  const int n0 = blockIdx.y * 128;
  const float* A = (job == 0) ? Qin : (job == 1) ? Kin : Vin;

  // --- stage weight tile [k=0..255][n=n0..n0+127] into Wl[n][k] (bf16) ---
  if (job < 3) {
    // src is [k=256][n=256]; transpose. Coalesced along n (128 lanes/row).
    const float* src = (job == 0) ? QT : (job == 1) ? KT : VTr;
    const int nl = tid & 127;
    const int kq = (tid >> 7) * 4;  // 0 or 4
#pragma unroll 8
    for (int i = 0; i < 32; ++i) {
      int k0 = i * 8 + kq;
      float f0 = src[(size_t)(k0 + 0) * 256 + n0 + nl];
      float f1 = src[(size_t)(k0 + 1) * 256 + n0 + nl];
      float f2 = src[(size_t)(k0 + 2) * 256 + n0 + nl];
      float f3 = src[(size_t)(k0 + 3) * 256 + n0 + nl];
      bf16x4 w4;
      w4[0] = (bf16_t)f0; w4[1] = (bf16_t)f1; w4[2] = (bf16_t)f2; w4[3] = (bf16_t)f3;
      *(bf16x4*)&Wl[nl][k0] = w4;
    }
  } else {
    // GW is [n=256][k=256] (nn.Linear [out,in]); straight cast.
    const int kk = (tid & 63) * 4;
    const int nw = tid >> 6;
#pragma unroll 8
    for (int i = 0; i < 32; ++i) {
      int n = i * 4 + nw;
      float4 v = *(const float4*)(GW + (size_t)(n0 + n) * 256 + kk);
      bf16x4 w4;
      w4[0] = (bf16_t)v.x; w4[1] = (bf16_t)v.y; w4[2] = (bf16_t)v.z; w4[3] = (bf16_t)v.w;
      *(bf16x4*)&Wl[n][kk] = w4;
    }
  }
  __syncthreads();

  const f32x4 zf = {0.f, 0.f, 0.f, 0.f};
  f32x4 acc[2][8];
#pragma unroll
  for (int mi = 0; mi < 2; ++mi)
#pragma unroll
    for (int nf = 0; nf < 8; ++nf) acc[mi][nf] = zf;

  for (int kc = 0; kc < 8; ++kc) {
    bf16x8 a[2];
#pragma unroll
    for (int mi = 0; mi < 2; ++mi) {
      const float* ap = A + (size_t)(m0 + mi * 64 + t15) * 256 + kc * 32 + quad * 8;
      float4 x0 = *(const float4*)ap;
      float4 x1 = *(const float4*)(ap + 4);
      a[mi] = cvt8(x0, x1);
    }
#pragma unroll
    for (int nf = 0; nf < 8; ++nf) {
      bf16x4 lo = *(const bf16x4*)&Wl[nf * 16 + t15][kc * 32 + quad * 8];
      bf16x4 hi = *(const bf16x4*)&Wl[nf * 16 + t15][kc * 32 + quad * 8 + 4];
      bf16x8 bw = join8(lo, hi);
#pragma unroll
      for (int mi = 0; mi < 2; ++mi) acc[mi][nf] = MFMA(a[mi], bw, acc[mi][nf]);
    }
  }

  if (job == 2) {
    // Wl is dead; alias it as Sl[n=128][stride 136] and transpose in LDS so
    // the [h,c,s] global store is s-contiguous per 16-lane group.
    __syncthreads();
    bf16_t* Sb = &Wl[0][0];
#pragma unroll
    for (int mi = 0; mi < 2; ++mi) {
      const int m = mi * 64 + w * 16 + quad * 4;
#pragma unroll
      for (int nf = 0; nf < 8; ++nf) {
        const int n = nf * 16 + t15;
#pragma unroll
        for (int r = 0; r < 4; ++r) Sb[n * 136 + m + r] = (bf16_t)acc[mi][nf][r];
      }
    }
    __syncthreads();
    const int mloc = (tid & 15) * 8;  // lanes 0..15 cover 128 m-rows
    const int nl2 = tid >> 4;         // 16 n-columns per pass
    const int mg = blockIdx.x * 128 + mloc;
    const int bb = mg >> 11, s = mg & 2047;
#pragma unroll
    for (int p = 0; p < 8; ++p) {
      const int ng = n0 + p * 16 + nl2;
      const int hh = ng >> 5, c = ng & 31;
      bf16x8 v = *(const bf16x8*)&Sb[(p * 16 + nl2) * 136 + mloc];
      *(bf16x8*)(VT + (size_t)((bb * 8 + hh) * 32 + c) * 2048 + s) = v;
    }
  } else if (job == 3) {
#pragma unroll
    for (int mi = 0; mi < 2; ++mi) {
      const int mm0 = m0 + mi * 64 + quad * 4;
#pragma unroll
      for (int nf = 0; nf < 8; ++nf) {
        int nn = n0 + nf * 16 + t15;
        float bias = Gb[nn];
#pragma unroll
        for (int r = 0; r < 4; ++r) {
          float g = 1.f / (1.f + __expf(-(acc[mi][nf][r] + bias)));
          G[(size_t)(mm0 + r) * 256 + nn] = (bf16_t)g;
        }
      }
    }
  } else {
    bf16_t* dst = (job == 0) ? Qb : Kb;
#pragma unroll
    for (int mi = 0; mi < 2; ++mi) {
      const int mm0 = m0 + mi * 64 + quad * 4;
#pragma unroll
      for (int nf = 0; nf < 8; ++nf) {
        int nn = n0 + nf * 16 + t15;
#pragma unroll
        for (int r = 0; r < 4; ++r)
          dst[(size_t)(mm0 + r) * 256 + nn] = (bf16_t)acc[mi][nf][r];
      }
    }
  }
}

// ---------------------------------------------------------------------------
// Kernel 2: fused windowed attention + gating + output projection.
// 512 threads = 8 waves; wave h handles head h of one 16-query tile.
// V B-fragments + gate values prefetched before the score phase. P tile is
// WAVE-PRIVATE (written and read only by wave h) => no barrier between
// softmax and PV; the only __syncthreads is before the out-projection
// (cross-wave Ol reads). Out-projection consumes pre-converted bf16 OWb.
// XCD-swizzled block mapping keeps neighboring q-tiles on one XCD L2.
// grid = B*S/16 = 256 blocks.
// ---------------------------------------------------------------------------
__global__ __launch_bounds__(512) void attn_out_kernel(
    const bf16_t* __restrict__ Qb, const bf16_t* __restrict__ Kb,
    const bf16_t* __restrict__ VT, const bf16_t* __restrict__ G,
    const bf16_t* __restrict__ OWb, const float* __restrict__ Ob,
    float* __restrict__ out) {
  __shared__ bf16_t P[8][16][104];  // per-wave P tile (C->A layout transform)
  __shared__ bf16_t Ol[16][WK];     // gated attention output tile, [q_local][k]
  const int tid = threadIdx.x, h = tid >> 6, lane = tid & 63;
  const int quad = lane >> 4, t15 = lane & 15;
  // XCD-aware swizzle: 256 blocks = 8 XCDs x 32 contiguous q-tiles (bijective)
  const int bid = ((blockIdx.x & 7) << 5) | (blockIdx.x >> 3);
  const int qt = bid & 127, b = bid >> 7;
  const int q0 = qt * 16, tbase = q0 - 32;
  const size_t rowbase = (size_t)b * 2048;

  // Q A-fragment (K=32 = full head dim)
  bf16x8 aq = *(const bf16x8*)(Qb + (rowbase + q0 + t15) * 256 + h * 32 + quad * 8);

  // prefetch V B-fragments — independent of scores, hides latency under QK^T
  bf16x8 bv[3][2];
#pragma unroll
  for (int kc = 0; kc < 3; ++kc) {
    int ts = tbase + kc * 32 + quad * 8;  // multiple of 8: chunk fully in/out
    bv[kc][0] = zero_bf16x8();
    bv[kc][1] = zero_bf16x8();
    if (ts >= 0 && ts + 8 <= 2048) {
      const bf16_t* vb = VT + ((size_t)((b * 8 + h) * 32) + t15) * 2048 + ts;
      bv[kc][0] = *(const bf16x8*)vb;
      bv[kc][1] = *(const bf16x8*)(vb + (size_t)16 * 2048);
    }
  }

  // prefetch gate values (used only after PV)
  float g0[4], g1[4];
#pragma unroll
  for (int r = 0; r < 4; ++r) {
    size_t base = (rowbase + q0 + quad * 4 + r) * 256 + h * 32;
    g0[r] = (float)G[base + t15];
    g1[r] = (float)G[base + 16 + t15];
  }
  const float ob0 = Ob[h * 32 + t15];
  const float ob1 = Ob[h * 32 + 16 + t15];

  const f32x4 zf = {0.f, 0.f, 0.f, 0.f};
  f32x4 sc[5];
#pragma unroll
  for (int j = 0; j < 5; ++j) {
    int t = tbase + j * 16 + t15;
    bf16x8 bk = zero_bf16x8();
    if ((unsigned)t < 2048u)
      bk = *(const bf16x8*)(Kb + (rowbase + t) * 256 + h * 32 + quad * 8);
    sc[j] = MFMA(aq, bk, zf);
  }

  const float scale = 0.17677669529663687f;  // 1/sqrt(32)
  float mx[4] = {-3.0e38f, -3.0e38f, -3.0e38f, -3.0e38f};
#pragma unroll
  for (int j = 0; j < 5; ++j) {
    int t = tbase + j * 16 + t15;
#pragma unroll
    for (int r = 0; r < 4; ++r) {
      int q = q0 + quad * 4 + r;
      int dd = q - t;
      bool valid = ((unsigned)t < 2048u) && (dd <= 32) && (dd >= -32);
      float v = valid ? sc[j][r] * scale : -1e30f;
      sc[j][r] = v;
      mx[r] = fmaxf(mx[r], v);
    }
  }
#pragma unroll
  for (int off = 1; off < 16; off <<= 1) {
#pragma unroll
    for (int r = 0; r < 4; ++r) mx[r] = fmaxf(mx[r], __shfl_xor(mx[r], off));
  }
  float sum[4] = {0.f, 0.f, 0.f, 0.f};
#pragma unroll
  for (int j = 0; j < 5; ++j) {
#pragma unroll
    for (int r = 0; r < 4; ++r) {
      float e = __expf(sc[j][r] - mx[r]);
      sc[j][r] = e;
      sum[r] += e;
    }
  }
#pragma unroll
  for (int off = 1; off < 16; off <<= 1) {
#pragma unroll
    for (int r = 0; r < 4; ++r) sum[r] += __shfl_xor(sum[r], off);
  }
  float inv[4];
#pragma unroll
  for (int r = 0; r < 4; ++r) inv[r] = 1.f / sum[r];

  // C-layout -> LDS rows q_local, cols t_local (80..95 zero pad).
  // P[h] is wave-private: same-wave DS ordering + compiler lgkmcnt make a
  // block barrier unnecessary here.
#pragma unroll
  for (int j = 0; j < 5; ++j) {
#pragma unroll
    for (int r = 0; r < 4; ++r)
      P[h][quad * 4 + r][j * 16 + t15] = (bf16_t)(sc[j][r] * inv[r]);
  }
#pragma unroll
  for (int r = 0; r < 4; ++r) P[h][quad * 4 + r][80 + t15] = (bf16_t)0.f;

  f32x4 y0 = zf, y1 = zf;
#pragma unroll
  for (int kc = 0; kc < 3; ++kc) {
    bf16x8 pa = *(const bf16x8*)&P[h][t15][kc * 32 + quad * 8];
    y0 = MFMA(pa, bv[kc][0], y0);
    y1 = MFMA(pa, bv[kc][1], y1);
  }

  // gate and gather the 16x256 O tile into LDS
#pragma unroll
  for (int r = 0; r < 4; ++r) {
    Ol[quad * 4 + r][h * 32 + t15] = (bf16_t)(y0[r] * g0[r]);
    Ol[quad * 4 + r][h * 32 + 16 + t15] = (bf16_t)(y1[r] * g1[r]);
  }
  __syncthreads();

  // out-projection: wave h computes out[:, h*32 .. h*32+32) from bf16 OWb
  f32x4 acc[2] = {zf, zf};
#pragma unroll
  for (int kc = 0; kc < 8; ++kc) {
    bf16x4 alo = *(const bf16x4*)&Ol[t15][kc * 32 + quad * 8];
    bf16x4 ahi = *(const bf16x4*)&Ol[t15][kc * 32 + quad * 8 + 4];
    bf16x8 a = join8(alo, ahi);
#pragma unroll
    for (int nf = 0; nf < 2; ++nf) {
      int n = h * 32 + nf * 16 + t15;
      bf16x8 w8 = *(const bf16x8*)(OWb + (size_t)n * 256 + kc * 32 + quad * 8);
      acc[nf] = MFMA(a, w8, acc[nf]);
    }
  }
#pragma unroll
  for (int nf = 0; nf < 2; ++nf) {
    int n = h * 32 + nf * 16 + t15;
    float bias = (nf == 0) ? ob0 : ob1;
#pragma unroll
    for (int r = 0; r < 4; ++r)
      out[(rowbase + q0 + quad * 4 + r) * 256 + n] = acc[nf][r] + bias;
  }
}

// ---------------------------------------------------------------------------
extern "C" void kernel_launch(void* const* d_in, const int* in_sizes, int n_in,
                              void* d_out, int out_size, void* d_ws, size_t ws_size,
                              hipStream_t stream) {
  const float* Qin = (const float*)d_in[0];
  const float* Kin = (const float*)d_in[1];
  const float* Vin = (const float*)d_in[2];
  const float* QT  = (const float*)d_in[3];
  const float* KT  = (const float*)d_in[4];
  const float* VTr = (const float*)d_in[5];
  const float* GW  = (const float*)d_in[6];
  const float* Gb  = (const float*)d_in[7];
  const float* OW  = (const float*)d_in[8];
  const float* Ob  = (const float*)d_in[9];
  float* out = (float*)d_out;

  char* ws = (char*)d_ws;
  const size_t MB = 1u << 20;
  bf16_t* Qb  = (bf16_t*)(ws + 0 * MB);  // [B,S,256] bf16, 2 MB
  bf16_t* Kb  = (bf16_t*)(ws + 2 * MB);  // [B,S,256] bf16, 2 MB
  bf16_t* VT  = (bf16_t*)(ws + 4 * MB);  // [B,H,C,S] bf16, 2 MB
  bf16_t* G   = (bf16_t*)(ws + 6 * MB);  // [B,S,256] bf16, 2 MB
  bf16_t* OWb = (bf16_t*)(ws + 8 * MB);  // [256,256] bf16, 128 KB

  proj_kernel<<<dim3(32, 2, 5), 256, 0, stream>>>(Qin, Kin, Vin, QT, KT, VTr,
                                                  GW, Gb, OW, Qb, Kb, VT, G, OWb);
  attn_out_kernel<<<256, 512, 0, stream>>>(Qb, Kb, VT, G, OWb, Ob, out);
}